// Round 8
// baseline (309.555 us; speedup 1.0000x reference)
//
#include <hip/hip_runtime.h>
#include <hip/hip_bf16.h>

// TT-linear: out(8192x4096) = x @ W, W from TT cores g1,g2.
// (1) prep: cvt x->bf16 + build W^T bf16. (2) GEMM: 8-phase/2-K-tile template,
//     256x256 tile, BK=64, 2dbuf, 1 half-tile stage/phase, counted vmcnt(4) at
//     ph4/ph8, setprio, chunk^(row&7) swizzle (R6/R7-verified 0-conflict).
// R7->R8: (a) 32x32x16 MFMA (2495 vs 2075 TF pipe; same LDS reads/layout),
//         (b) removed explicit LGKM8/LGKM0 — compiler emits per-consumer
//             counted lgkmcnt -> waves stagger, LDS service overlaps MFMA.

#define TOKENS 8192
#define KDIM 4096
#define NDIM 4096

typedef __attribute__((ext_vector_type(8))) __bf16 bf16x8;
typedef __attribute__((ext_vector_type(16))) float f32x16;
typedef __attribute__((ext_vector_type(8))) unsigned short u16x8;

typedef __attribute__((address_space(1))) unsigned int as1_uint;
typedef __attribute__((address_space(3))) unsigned int as3_uint;

#define GLOAD_LDS16(gp, lp) \
  __builtin_amdgcn_global_load_lds((as1_uint*)(void*)(gp), (as3_uint*)(void*)(lp), 16, 0, 0)

#define BAR() asm volatile("s_barrier" ::: "memory")
#define VMCNT4() asm volatile("s_waitcnt vmcnt(4)" ::: "memory")

__device__ inline unsigned short f2bf(float f) {
  __hip_bfloat16 h = __float2bfloat16(f);
  return __builtin_bit_cast(unsigned short, h);
}

// ---------------- Kernel 1: merged prep (cvt x -> bf16 ; build Wt[n][k] bf16) ----------------
__global__ __launch_bounds__(256) void prep_kernel(const float* __restrict__ x,
                                                   const float* __restrict__ g1,
                                                   const float* __restrict__ g2,
                                                   unsigned short* __restrict__ xb,
                                                   unsigned short* __restrict__ wt) {
  __shared__ float a_s[64 * 16];  // [m1][r] for fixed n1
  __shared__ float b_s[16 * 64];  // [r][m2] for fixed n2
  const int bid = blockIdx.x;
  const int t = threadIdx.x;

  if (bid < 16384) {
    size_t i = (size_t)bid * 256 + t;
    const float4* p = reinterpret_cast<const float4*>(x) + i * 2;
    float4 v0 = p[0];
    float4 v1 = p[1];
    u16x8 u;
    u[0] = f2bf(v0.x); u[1] = f2bf(v0.y); u[2] = f2bf(v0.z); u[3] = f2bf(v0.w);
    u[4] = f2bf(v1.x); u[5] = f2bf(v1.y); u[6] = f2bf(v1.z); u[7] = f2bf(v1.w);
    reinterpret_cast<u16x8*>(xb)[i] = u;
    return;
  }

  const int n = bid - 16384;
  const int n1 = n >> 6, n2 = n & 63;
  for (int e = t; e < 1024; e += 256) {
    int m1 = e >> 4, r = e & 15;
    a_s[e] = g1[m1 * 1024 + n1 * 16 + r];
  }
  for (int e = t; e < 1024; e += 256) {
    int r = e >> 6, m2 = e & 63;
    b_s[e] = g2[r * 4096 + m2 * 64 + n2];
  }
  __syncthreads();

  unsigned short loc[16];
  const int kbase = t * 16;
#pragma unroll
  for (int kk = 0; kk < 16; ++kk) {
    int k = kbase + kk;
    int m1 = k >> 6, m2 = k & 63;
    float acc = 0.f;
#pragma unroll
    for (int r = 0; r < 16; ++r) acc += a_s[m1 * 16 + r] * b_s[r * 64 + m2];
    loc[kk] = f2bf(acc);
  }
  u16x8* dst = reinterpret_cast<u16x8*>(wt + (size_t)n * KDIM + kbase);
  dst[0] = *reinterpret_cast<u16x8*>(&loc[0]);
  dst[1] = *reinterpret_cast<u16x8*>(&loc[8]);
}

// ---------------- Kernel 2: GEMM 256x256, BK=64, 8-phase/2-K-tile, 32x32x16 ----------------
// out[m][n] = sum_k Xb[m][k] * Wt[n][k].
// LDS: buf0 @0 (even K-tiles), buf1 @65536 (odd): A[256][64]bf16 @+0, B @+32768.
// Row = 128B = 8 chunks; swizzle chunk' = chunk ^ (row&7).
// Wave = 128x64 out = 4 i-frags (32 rows) x 2 j-frags (32 cols), acc f32x16[4][2].
// Per K-tile (4 phases x 8 MFMA, reads consumed same-phase -> compiler lgkm waits):
//   ph1: rd a0-1 kk0-3 (8) + b0 kk0-3 (4); stage; BAR; MFMA (i0-1)x(j0)
//   ph2: rd a2-3 kk0-3 (8);                stage; BAR; MFMA (i2-3)x(j0)
//   ph3: rd b1 kk0-3 (4);                  stage; BAR; MFMA (i0-1)x(j1)
//   ph4:                                   stage; vmcnt(4); BAR; MFMA (i2-3)x(j1)
// Stage slots (1 half-tile = 2 gloads), iter u = tiles (2u, 2u+1):
//   ph1: B-h0(2u+1) ph2: B-h1(2u+1) ph3: A-h0(2u+2) ph4: A-h1(2u+2)+vmcnt(4)
//   ph5: B-h0(2u+2) ph6: B-h1(2u+2) ph7: A-h0(2u+3) ph8: A-h1(2u+3)+vmcnt(4)
// Ledger (loads): ph4 outstanding = {B(t1):4, A(t2):4}; vmcnt(4) -> B(t1) done.
// ph8 outstanding = {A(t2):4, B(t2):4, A(t3):4}; vmcnt(4) -> tile t2 done.
__global__ __launch_bounds__(512, 2) void gemm_kernel(const unsigned short* __restrict__ Xb,
                                                      const unsigned short* __restrict__ Wt,
                                                      float* __restrict__ out) {
  __shared__ __align__(16) char lds[131072];

  const int t = threadIdx.x;
  const int lane = t & 63;
  const int wave = t >> 6;   // 0..7
  const int wm = wave >> 2;  // 0..1 : 128 output rows
  const int wn = wave & 3;   // 0..3 : 64 output cols

  // 8x8-per-XCD chunking
  const int bid = blockIdx.x;
  const int xcd = bid & 7, jj = bid >> 3;
  const int bm = ((xcd >> 1) << 3) + (jj >> 3);
  const int bn = ((xcd & 1) << 3) + (jj & 7);
  const int m0 = bm << 8, n0 = bn << 8;

  // staging: thread t -> row t>>3 (0..63 per gload), lds chunk t&7,
  // inverse-swizzled source chunk (t&7)^((t>>3)&7).
  const int srow = t >> 3;
  const int csrc = (t & 7) ^ ((t >> 3) & 7);
  const unsigned short* aS = Xb + (size_t)(m0 + srow) * KDIM + csrc * 8;
  const unsigned short* bS = Wt + (size_t)(n0 + srow) * KDIM + csrc * 8;
  const int ldsW = wave << 10;  // wave-uniform 1KB slot

#define STGH_A(kt, bb, h) do { \
    const unsigned short* _s = aS + (size_t)((h) * 128) * KDIM + (size_t)(kt) * 64; \
    GLOAD_LDS16(_s, lds + (bb) + (h) * 16384 + ldsW); \
    GLOAD_LDS16(_s + (size_t)64 * KDIM, lds + (bb) + (h) * 16384 + 8192 + ldsW); \
  } while (0)
#define STGH_B(kt, bb, h) do { \
    const unsigned short* _s = bS + (size_t)((h) * 128) * KDIM + (size_t)(kt) * 64; \
    GLOAD_LDS16(_s, lds + (bb) + 32768 + (h) * 16384 + ldsW); \
    GLOAD_LDS16(_s + (size_t)64 * KDIM, lds + (bb) + 32768 + (h) * 16384 + 8192 + ldsW); \
  } while (0)

  // fragment reads (32x32x16): row = base32 + (lane&31); chunk = kk*2 + (lane>>5);
  // lds chunk = chunk ^ (row&7) = chunk ^ (lane&7); kk adds 2 to chunk (no carry)
  // -> byte offset XOR (kk*0x20).
  const int cO = ((lane >> 5) ^ (lane & 7)) << 4;
  const int aRowB = (wm * 128 + (lane & 31)) * 128;          // + i*4096 (+rb)
  const int bRowB = 32768 + (wn * 64 + (lane & 31)) * 128;   // + j*4096 (+rb)

#define RA(i, kk, rb) (*(const bf16x8*)(lds + (rb) + aRowB + (i) * 4096 + (cO ^ ((kk) * 32))))
#define RB(j, kk, rb) (*(const bf16x8*)(lds + (rb) + bRowB + (j) * 4096 + (cO ^ ((kk) * 32))))
#define MF(i, j, A, B) acc[i][j] = __builtin_amdgcn_mfma_f32_32x32x16_bf16((A), (B), acc[i][j], 0, 0, 0)

  f32x16 acc[4][2];
#pragma unroll
  for (int i = 0; i < 4; ++i)
#pragma unroll
    for (int j = 0; j < 2; ++j)
#pragma unroll
      for (int e = 0; e < 16; ++e) acc[i][j][e] = 0.f;

  // 4-phase body for one K-tile at LDS base RB_; S1..S4 = stage statements.
#define KTILE(RB_, S1, S2, S3, S4, W4) do { \
    /* ph1: a0-1 (all kk) + b0 (all kk) */ \
    bf16x8 a00 = RA(0, 0, RB_), a01 = RA(0, 1, RB_), a02 = RA(0, 2, RB_), a03 = RA(0, 3, RB_); \
    bf16x8 a10 = RA(1, 0, RB_), a11 = RA(1, 1, RB_), a12 = RA(1, 2, RB_), a13 = RA(1, 3, RB_); \
    bf16x8 b00 = RB(0, 0, RB_), b01 = RB(0, 1, RB_), b02 = RB(0, 2, RB_), b03 = RB(0, 3, RB_); \
    S1; BAR(); \
    __builtin_amdgcn_s_setprio(1); \
    MF(0, 0, a00, b00); MF(1, 0, a10, b00); MF(0, 0, a01, b01); MF(1, 0, a11, b01); \
    MF(0, 0, a02, b02); MF(1, 0, a12, b02); MF(0, 0, a03, b03); MF(1, 0, a13, b03); \
    __builtin_amdgcn_s_setprio(0); BAR(); \
    /* ph2: a2-3 (all kk) */ \
    bf16x8 a20 = RA(2, 0, RB_), a21 = RA(2, 1, RB_), a22 = RA(2, 2, RB_), a23 = RA(2, 3, RB_); \
    bf16x8 a30 = RA(3, 0, RB_), a31 = RA(3, 1, RB_), a32 = RA(3, 2, RB_), a33 = RA(3, 3, RB_); \
    S2; BAR(); \
    __builtin_amdgcn_s_setprio(1); \
    MF(2, 0, a20, b00); MF(3, 0, a30, b00); MF(2, 0, a21, b01); MF(3, 0, a31, b01); \
    MF(2, 0, a22, b02); MF(3, 0, a32, b02); MF(2, 0, a23, b03); MF(3, 0, a33, b03); \
    __builtin_amdgcn_s_setprio(0); BAR(); \
    /* ph3: b1 (all kk) */ \
    bf16x8 b10 = RB(1, 0, RB_), b11 = RB(1, 1, RB_), b12 = RB(1, 2, RB_), b13 = RB(1, 3, RB_); \
    S3; BAR(); \
    __builtin_amdgcn_s_setprio(1); \
    MF(0, 1, a00, b10); MF(1, 1, a10, b10); MF(0, 1, a01, b11); MF(1, 1, a11, b11); \
    MF(0, 1, a02, b12); MF(1, 1, a12, b12); MF(0, 1, a03, b13); MF(1, 1, a13, b13); \
    __builtin_amdgcn_s_setprio(0); BAR(); \
    /* ph4: no reads */ \
    S4; W4; BAR(); \
    __builtin_amdgcn_s_setprio(1); \
    MF(2, 1, a20, b10); MF(3, 1, a30, b10); MF(2, 1, a21, b11); MF(3, 1, a31, b11); \
    MF(2, 1, a22, b12); MF(3, 1, a32, b12); MF(2, 1, a23, b13); MF(3, 1, a33, b13); \
    __builtin_amdgcn_s_setprio(0); BAR(); \
  } while (0)

  // ---- prologue: tile0 -> buf0, tile1's A -> buf1; vmcnt(4) -> tile0 resident ----
  STGH_A(0, 0, 0); STGH_A(0, 0, 1); STGH_B(0, 0, 0); STGH_B(0, 0, 1);
  STGH_A(1, 65536, 0); STGH_A(1, 65536, 1);
  VMCNT4();
  BAR();

#pragma unroll 1
  for (int u = 0; u < 32; ++u) {
    const int t1 = 2 * u + 1;
    const int t2n = (2 * u + 2) & 63;  // wraps at u=31 -> dummy re-stage, never read
    const int t3n = (2 * u + 3) & 63;

    KTILE(0,
          STGH_B(t1, 65536, 0),
          STGH_B(t1, 65536, 1),
          STGH_A(t2n, 0, 0),
          STGH_A(t2n, 0, 1),
          VMCNT4());

    KTILE(65536,
          STGH_B(t2n, 0, 0),
          STGH_B(t2n, 0, 1),
          STGH_A(t3n, 65536, 0),
          STGH_A(t3n, 65536, 1),
          VMCNT4());
  }

  // ---- epilogue: 32x32 C/D: col = lane&31, row = (reg&3) + 8*(reg>>2) + 4*(lane>>5) ----
  const int ccol = lane & 31;
  const int r0 = (lane >> 5) << 2;
#pragma unroll
  for (int i = 0; i < 4; ++i) {
#pragma unroll
    for (int j = 0; j < 2; ++j) {
      size_t base = (size_t)(m0 + wm * 128 + i * 32 + r0) * NDIM + (n0 + wn * 64 + j * 32 + ccol);
#pragma unroll
      for (int reg = 0; reg < 16; ++reg) {
        int row = (reg & 3) + ((reg >> 2) << 3);
        out[base + (size_t)row * NDIM] = acc[i][j][reg];
      }
    }
  }
}

extern "C" void kernel_launch(void* const* d_in, const int* in_sizes, int n_in,
                              void* d_out, int out_size, void* d_ws, size_t ws_size,
                              hipStream_t stream) {
  const float* x = (const float*)d_in[0];
  const float* g1 = (const float*)d_in[1];
  const float* g2 = (const float*)d_in[2];
  float* out = (float*)d_out;

  unsigned short* Wt = (unsigned short*)d_ws;
  unsigned short* Xb = (unsigned short*)d_ws + (size_t)KDIM * NDIM;

  prep_kernel<<<16384 + NDIM, 256, 0, stream>>>(x, g1, g2, Xb, Wt);
  gemm_kernel<<<(TOKENS / 256) * (NDIM / 256), 512, 0, stream>>>(Xb, Wt, out);
}

// Round 9
// 288.933 us; speedup vs baseline: 1.0714x; 1.0714x over previous
//
#include <hip/hip_runtime.h>
#include <hip/hip_bf16.h>

// TT-linear: out(8192x4096) = x @ W, W from TT cores g1,g2.
// (1) prep: cvt x->bf16 + build W^T bf16. (2) GEMM: 256x256 tile, BK=32,
//     UNIFIED [256 rows][A-32k|B-32k] 32KB tiles, 4-buffer ring (128KB),
//     1 phase/K-tile READ-AHEAD pipeline: phase p = {read tile p+1 frags,
//     stage tile p+3, MFMA tile p (prev-phase frags)}, vmcnt(4)/phase.
// R8->R9: reverted to R7's 0-conflict read geometry (128B rows, 16-row frags);
//     decoupled LDS reads from MFMA (read-ahead) to overlap the 768-cyc LDS
//     service under the 1241-cyc MFMA pipe (R7 had them serialized).

#define TOKENS 8192
#define KDIM 4096
#define NDIM 4096

typedef __attribute__((ext_vector_type(8))) __bf16 bf16x8;
typedef __attribute__((ext_vector_type(4))) float f32x4;
typedef __attribute__((ext_vector_type(8))) unsigned short u16x8;

typedef __attribute__((address_space(1))) unsigned int as1_uint;
typedef __attribute__((address_space(3))) unsigned int as3_uint;

#define GLOAD_LDS16(gp, lp) \
  __builtin_amdgcn_global_load_lds((as1_uint*)(void*)(gp), (as3_uint*)(void*)(lp), 16, 0, 0)

#define BAR() asm volatile("s_barrier" ::: "memory")
#define VMCNT4() asm volatile("s_waitcnt vmcnt(4)" ::: "memory")

__device__ inline unsigned short f2bf(float f) {
  __hip_bfloat16 h = __float2bfloat16(f);
  return __builtin_bit_cast(unsigned short, h);
}

// ---------------- Kernel 1: merged prep (cvt x -> bf16 ; build Wt[n][k] bf16) ----------------
__global__ __launch_bounds__(256) void prep_kernel(const float* __restrict__ x,
                                                   const float* __restrict__ g1,
                                                   const float* __restrict__ g2,
                                                   unsigned short* __restrict__ xb,
                                                   unsigned short* __restrict__ wt) {
  __shared__ float a_s[64 * 16];  // [m1][r] for fixed n1
  __shared__ float b_s[16 * 64];  // [r][m2] for fixed n2
  const int bid = blockIdx.x;
  const int t = threadIdx.x;

  if (bid < 16384) {
    size_t i = (size_t)bid * 256 + t;
    const float4* p = reinterpret_cast<const float4*>(x) + i * 2;
    float4 v0 = p[0];
    float4 v1 = p[1];
    u16x8 u;
    u[0] = f2bf(v0.x); u[1] = f2bf(v0.y); u[2] = f2bf(v0.z); u[3] = f2bf(v0.w);
    u[4] = f2bf(v1.x); u[5] = f2bf(v1.y); u[6] = f2bf(v1.z); u[7] = f2bf(v1.w);
    reinterpret_cast<u16x8*>(xb)[i] = u;
    return;
  }

  const int n = bid - 16384;
  const int n1 = n >> 6, n2 = n & 63;
  for (int e = t; e < 1024; e += 256) {
    int m1 = e >> 4, r = e & 15;
    a_s[e] = g1[m1 * 1024 + n1 * 16 + r];
  }
  for (int e = t; e < 1024; e += 256) {
    int r = e >> 6, m2 = e & 63;
    b_s[e] = g2[r * 4096 + m2 * 64 + n2];
  }
  __syncthreads();

  unsigned short loc[16];
  const int kbase = t * 16;
#pragma unroll
  for (int kk = 0; kk < 16; ++kk) {
    int k = kbase + kk;
    int m1 = k >> 6, m2 = k & 63;
    float acc = 0.f;
#pragma unroll
    for (int r = 0; r < 16; ++r) acc += a_s[m1 * 16 + r] * b_s[r * 64 + m2];
    loc[kk] = f2bf(acc);
  }
  u16x8* dst = reinterpret_cast<u16x8*>(wt + (size_t)n * KDIM + kbase);
  dst[0] = *reinterpret_cast<u16x8*>(&loc[0]);
  dst[1] = *reinterpret_cast<u16x8*>(&loc[8]);
}

// ---------------- Kernel 2: GEMM 256x256, BK=32, 4-buf ring, read-ahead pipeline ----------------
// out[m][n] = sum_k Xb[m][k] * Wt[n][k].
// Tile t lives in buf t&3 (32KB @ (t&3)*32768): row r (0..255) = 128B:
//   chunks 0-3 = A[r][k0..31] (r = tile m-row), chunks 4-7 = B[r][k0..31] (r = n-row).
// Swizzle chunk' = chunk ^ (row&7)  [R7-verified family: 0 conflicts].
// Phase p: {RDP: 12 ds_read_b128 of tile p+1 frags -> set (p+1)&1;
//           STG: 4 gloads of tile (p+3)&127 -> buf (p+3)&3;
//           sched_barrier; MFMA x32 on set p&1 (tile p, read last phase);
//           vmcnt(4) [drains tile p+2, issued @p-1]; s_barrier}.
// RAW: reads(tile p+1)@p staged @p-2, drained by vmcnt(4)@end(p-1) (age 1.7 ph).
// WAR: STG@p hits buf of tile p-1, whose reads (issued @p-2) were lgkm-drained
//      by the MFMA @p-1 before its end barrier.
__global__ __launch_bounds__(512, 2) void gemm_kernel(const unsigned short* __restrict__ Xb,
                                                      const unsigned short* __restrict__ Wt,
                                                      float* __restrict__ out) {
  __shared__ __align__(16) char lds[131072];

  const int t = threadIdx.x;
  const int lane = t & 63;
  const int wave = t >> 6;   // 0..7
  const int wm = wave >> 2;  // 0..1 : 128 output rows
  const int wn = wave & 3;   // 0..3 : 64 output cols

  // 8x8-per-XCD chunking
  const int bid = blockIdx.x;
  const int xcd = bid & 7, jj = bid >> 3;
  const int bm = ((xcd >> 1) << 3) + (jj >> 3);
  const int bn = ((xcd & 1) << 3) + (jj & 7);
  const int m0 = bm << 8, n0 = bn << 8;

  // staging: thread t -> row (t>>3) within a 64-row gload group, lds chunk t&7,
  // inverse-swizzled source chunk c = (t&7)^((t>>3)&7); c<4 -> A (Xb), else B (Wt).
  const int srow = t >> 3;
  const int c = (t & 7) ^ ((t >> 3) & 7);
  const unsigned short* gS =
      (c < 4) ? (Xb + (size_t)(m0 + srow) * KDIM + c * 8)
              : (Wt + (size_t)(n0 + srow) * KDIM + (c - 4) * 8);
  const int ldsW = wave << 10;  // wave-uniform 1KB slot
  const size_t GSTR = (size_t)64 * KDIM;  // 64-row advance (same for A and B)

#define STG(kt, bb) do { \
    const unsigned short* _s = gS + (size_t)(kt) * 32; \
    GLOAD_LDS16(_s,            lds + (bb) + ldsW); \
    GLOAD_LDS16(_s + GSTR,     lds + (bb) + 8192 + ldsW); \
    GLOAD_LDS16(_s + 2 * GSTR, lds + (bb) + 16384 + ldsW); \
    GLOAD_LDS16(_s + 3 * GSTR, lds + (bb) + 24576 + ldsW); \
  } while (0)

  // fragment reads: row = base16 + (lane&15); A chunk = lane>>4 (0-3), B chunk = 4+(lane>>4);
  // lds chunk = chunk ^ (row&7) = chunk ^ (lane&7); B differs from A by byte XOR 64.
  const int cO = ((lane >> 4) ^ (lane & 7)) << 4;
  const int aOff = (wm * 128 + (lane & 15)) * 128 + cO;          // + i*2048 (+buf)
  const int bOff = (wn * 64 + (lane & 15)) * 128 + (cO ^ 64);    // + j*2048 (+buf)

  bf16x8 fA[2][8], fB[2][4];

#define RDP(P, RB) do { \
    fA[P][0] = *(const bf16x8*)(lds + (RB) + aOff);           \
    fA[P][1] = *(const bf16x8*)(lds + (RB) + aOff + 2048);    \
    fA[P][2] = *(const bf16x8*)(lds + (RB) + aOff + 4096);    \
    fA[P][3] = *(const bf16x8*)(lds + (RB) + aOff + 6144);    \
    fA[P][4] = *(const bf16x8*)(lds + (RB) + aOff + 8192);    \
    fA[P][5] = *(const bf16x8*)(lds + (RB) + aOff + 10240);   \
    fA[P][6] = *(const bf16x8*)(lds + (RB) + aOff + 12288);   \
    fA[P][7] = *(const bf16x8*)(lds + (RB) + aOff + 14336);   \
    fB[P][0] = *(const bf16x8*)(lds + (RB) + bOff);           \
    fB[P][1] = *(const bf16x8*)(lds + (RB) + bOff + 2048);    \
    fB[P][2] = *(const bf16x8*)(lds + (RB) + bOff + 4096);    \
    fB[P][3] = *(const bf16x8*)(lds + (RB) + bOff + 6144);    \
  } while (0)

#define MF(i, j, P) acc[i][j] = __builtin_amdgcn_mfma_f32_16x16x32_bf16(fA[P][i], fB[P][j], acc[i][j], 0, 0, 0)
#define MMP(P) do { \
    MF(0, 0, P); MF(0, 1, P); MF(0, 2, P); MF(0, 3, P); \
    MF(1, 0, P); MF(1, 1, P); MF(1, 2, P); MF(1, 3, P); \
    MF(2, 0, P); MF(2, 1, P); MF(2, 2, P); MF(2, 3, P); \
    MF(3, 0, P); MF(3, 1, P); MF(3, 2, P); MF(3, 3, P); \
    MF(4, 0, P); MF(4, 1, P); MF(4, 2, P); MF(4, 3, P); \
    MF(5, 0, P); MF(5, 1, P); MF(5, 2, P); MF(5, 3, P); \
    MF(6, 0, P); MF(6, 1, P); MF(6, 2, P); MF(6, 3, P); \
    MF(7, 0, P); MF(7, 1, P); MF(7, 2, P); MF(7, 3, P); \
  } while (0)

#define PHASE(RBB, SBB, PC, PN, KT) do { \
    RDP(PN, RBB); \
    STG(KT, SBB); \
    __builtin_amdgcn_sched_barrier(0); \
    __builtin_amdgcn_s_setprio(1); \
    MMP(PC); \
    __builtin_amdgcn_s_setprio(0); \
    VMCNT4(); \
    BAR(); \
  } while (0)

  f32x4 acc[8][4];
#pragma unroll
  for (int i = 0; i < 8; ++i)
#pragma unroll
    for (int j = 0; j < 4; ++j) acc[i][j] = (f32x4){0.f, 0.f, 0.f, 0.f};

  // ---- prologue: stage tiles 0,1,2; vmcnt(4) -> tiles 0,1 resident; read tile0 ----
  STG(0, 0); STG(1, 32768); STG(2, 65536);
  VMCNT4();
  BAR();
  RDP(0, 0);

#pragma unroll 1
  for (int u = 0; u < 32; ++u) {
    const int p = u << 2;
    PHASE(32768, 98304, 0, 1, (p + 3) & 127);   // p%4==0: rd buf1, stg buf3
    PHASE(65536, 0,     1, 0, (p + 4) & 127);   // p%4==1: rd buf2, stg buf0
    PHASE(98304, 32768, 0, 1, (p + 5) & 127);   // p%4==2: rd buf3, stg buf1
    PHASE(0,     65536, 1, 0, (p + 6) & 127);   // p%4==3: rd buf0, stg buf2
  }

  // ---- epilogue: C/D layout col = lane&15, row = (lane>>4)*4 + q ----
  const int crow = (lane >> 4) << 2;
  const int ccol = lane & 15;
#pragma unroll
  for (int i = 0; i < 8; ++i) {
#pragma unroll
    for (int j = 0; j < 4; ++j) {
      size_t base = (size_t)(m0 + wm * 128 + i * 16 + crow) * NDIM + (n0 + wn * 64 + j * 16 + ccol);
#pragma unroll
      for (int q = 0; q < 4; ++q) out[base + (size_t)q * NDIM] = acc[i][j][q];
    }
  }
}

extern "C" void kernel_launch(void* const* d_in, const int* in_sizes, int n_in,
                              void* d_out, int out_size, void* d_ws, size_t ws_size,
                              hipStream_t stream) {
  const float* x = (const float*)d_in[0];
  const float* g1 = (const float*)d_in[1];
  const float* g2 = (const float*)d_in[2];
  float* out = (float*)d_out;

  unsigned short* Wt = (unsigned short*)d_ws;
  unsigned short* Xb = (unsigned short*)d_ws + (size_t)KDIM * NDIM;

  prep_kernel<<<16384 + NDIM, 256, 0, stream>>>(x, g1, g2, Xb, Wt);
  gemm_kernel<<<(TOKENS / 256) * (NDIM / 256), 512, 0, stream>>>(Xb, Wt, out);
}

// Round 10
// 284.555 us; speedup vs baseline: 1.0879x; 1.0154x over previous
//
#include <hip/hip_runtime.h>
#include <hip/hip_bf16.h>

// TT-linear: out(8192x4096) = x @ W, W from TT cores g1,g2.
// (1) prep: cvt x->bf16 + build W^T bf16. (2) GEMM: 256x256 tile, BK=32,
//     unified [256r][A|B] 32KB tiles, 4-buffer ring, read-ahead pipeline.
// R9->R10: fragment reads via INLINE-ASM ds_read_b128 + counted
//     "s_waitcnt lgkmcnt(12)" + sched_barrier(0) (rule #18 / m214 pattern).
//     R9's plain-C reads got a conservative compiler lgkmcnt(0) before each
//     MFMA cluster (asm barriers reset its counter tracking) -> reads and
//     MFMA fully serialized (wall == sum, verified vs counters R7-R9).
//     Now the 12 new reads drain UNDER the 32-MFMA cluster.

#define TOKENS 8192
#define KDIM 4096
#define NDIM 4096

typedef __attribute__((ext_vector_type(8))) __bf16 bf16x8;
typedef __attribute__((ext_vector_type(4))) float f32x4;
typedef __attribute__((ext_vector_type(8))) unsigned short u16x8;

typedef __attribute__((address_space(1))) unsigned int as1_uint;
typedef __attribute__((address_space(3))) unsigned int as3_uint;

#define GLOAD_LDS16(gp, lp) \
  __builtin_amdgcn_global_load_lds((as1_uint*)(void*)(gp), (as3_uint*)(void*)(lp), 16, 0, 0)

#define BAR() asm volatile("s_barrier" ::: "memory")
#define VMCNT4() asm volatile("s_waitcnt vmcnt(4)" ::: "memory")
#define LGKM12() asm volatile("s_waitcnt lgkmcnt(12)" ::: "memory")

__device__ inline unsigned short f2bf(float f) {
  __hip_bfloat16 h = __float2bfloat16(f);
  return __builtin_bit_cast(unsigned short, h);
}

// ---------------- Kernel 1: merged prep (cvt x -> bf16 ; build Wt[n][k] bf16) ----------------
__global__ __launch_bounds__(256) void prep_kernel(const float* __restrict__ x,
                                                   const float* __restrict__ g1,
                                                   const float* __restrict__ g2,
                                                   unsigned short* __restrict__ xb,
                                                   unsigned short* __restrict__ wt) {
  __shared__ float a_s[64 * 16];  // [m1][r] for fixed n1
  __shared__ float b_s[16 * 64];  // [r][m2] for fixed n2
  const int bid = blockIdx.x;
  const int t = threadIdx.x;

  if (bid < 16384) {
    size_t i = (size_t)bid * 256 + t;
    const float4* p = reinterpret_cast<const float4*>(x) + i * 2;
    float4 v0 = p[0];
    float4 v1 = p[1];
    u16x8 u;
    u[0] = f2bf(v0.x); u[1] = f2bf(v0.y); u[2] = f2bf(v0.z); u[3] = f2bf(v0.w);
    u[4] = f2bf(v1.x); u[5] = f2bf(v1.y); u[6] = f2bf(v1.z); u[7] = f2bf(v1.w);
    reinterpret_cast<u16x8*>(xb)[i] = u;
    return;
  }

  const int n = bid - 16384;
  const int n1 = n >> 6, n2 = n & 63;
  for (int e = t; e < 1024; e += 256) {
    int m1 = e >> 4, r = e & 15;
    a_s[e] = g1[m1 * 1024 + n1 * 16 + r];
  }
  for (int e = t; e < 1024; e += 256) {
    int r = e >> 6, m2 = e & 63;
    b_s[e] = g2[r * 4096 + m2 * 64 + n2];
  }
  __syncthreads();

  unsigned short loc[16];
  const int kbase = t * 16;
#pragma unroll
  for (int kk = 0; kk < 16; ++kk) {
    int k = kbase + kk;
    int m1 = k >> 6, m2 = k & 63;
    float acc = 0.f;
#pragma unroll
    for (int r = 0; r < 16; ++r) acc += a_s[m1 * 16 + r] * b_s[r * 64 + m2];
    loc[kk] = f2bf(acc);
  }
  u16x8* dst = reinterpret_cast<u16x8*>(wt + (size_t)n * KDIM + kbase);
  dst[0] = *reinterpret_cast<u16x8*>(&loc[0]);
  dst[1] = *reinterpret_cast<u16x8*>(&loc[8]);
}

// ---------------- Kernel 2: GEMM 256x256, BK=32, 4-buf ring, asm-read pipeline ----------------
// Tile t in buf t&3 (32KB @ (t&3)*32768): row r = 128B; chunks 0-3 = A[r][k], 4-7 = B[r][k].
// Swizzle chunk' = chunk ^ (row&7)  [verified 0-conflict family].
// Phase p: {12 asm ds_read_b128 of tile p+1 -> set (p+1)&1; 4 gloads tile p+3;
//           s_waitcnt lgkmcnt(12); sched_barrier(0);   <- tile p's reads complete,
//           setprio(1); 32 MFMA tile p; setprio(0);       new 12 drain under MFMA
//           vmcnt(4) [drains tile p+2's stage, issued @p-1]; s_barrier}.
// RAW: reads(tile p+1)@p staged @p-2, drained by vmcnt(4)@end(p-1).
// WAR: STG@p hits buf of tile p-1; its asm reads (issued @p-2) completed at the
//      lgkmcnt(12) in phase p-1 (only 12 newer outstanding), before p-1's barrier.
__global__ __launch_bounds__(512, 1) void gemm_kernel(const unsigned short* __restrict__ Xb,
                                                      const unsigned short* __restrict__ Wt,
                                                      float* __restrict__ out) {
  __shared__ __align__(16) char lds[131072];

  const int t = threadIdx.x;
  const int lane = t & 63;
  const int wave = t >> 6;   // 0..7
  const int wm = wave >> 2;  // 0..1 : 128 output rows
  const int wn = wave & 3;   // 0..3 : 64 output cols

  // 8x8-per-XCD chunking
  const int bid = blockIdx.x;
  const int xcd = bid & 7, jj = bid >> 3;
  const int bm = ((xcd >> 1) << 3) + (jj >> 3);
  const int bn = ((xcd & 1) << 3) + (jj & 7);
  const int m0 = bm << 8, n0 = bn << 8;

  // staging: thread t -> row (t>>3) within 64-row gload group, lds chunk t&7,
  // inverse-swizzled source chunk c = (t&7)^((t>>3)&7); c<4 -> A (Xb), else B (Wt).
  const int srow = t >> 3;
  const int c = (t & 7) ^ ((t >> 3) & 7);
  const unsigned short* gS =
      (c < 4) ? (Xb + (size_t)(m0 + srow) * KDIM + c * 8)
              : (Wt + (size_t)(n0 + srow) * KDIM + (c - 4) * 8);
  const int ldsW = wave << 10;  // wave-uniform 1KB slot
  const size_t GSTR = (size_t)64 * KDIM;

#define STG(kt, bb) do { \
    const unsigned short* _s = gS + (size_t)(kt) * 32; \
    GLOAD_LDS16(_s,            lds + (bb) + ldsW); \
    GLOAD_LDS16(_s + GSTR,     lds + (bb) + 8192 + ldsW); \
    GLOAD_LDS16(_s + 2 * GSTR, lds + (bb) + 16384 + ldsW); \
    GLOAD_LDS16(_s + 3 * GSTR, lds + (bb) + 24576 + ldsW); \
  } while (0)

  // fragment read addressing: row = base16 + (lane&15); A chunk = lane>>4, B = 4+(lane>>4);
  // lds chunk = chunk ^ (lane&7); B differs from A by byte XOR 64.
  const int cO = ((lane >> 4) ^ (lane & 7)) << 4;
  const int aOff = (wm * 128 + (lane & 15)) * 128 + cO;
  const int bOff = (wn * 64 + (lane & 15)) * 128 + (cO ^ 64);
  // LDS byte addresses (low 32 bits of generic pointer = LDS offset)
  const unsigned aAddr = (unsigned)(size_t)(lds + aOff);
  const unsigned bAddr = (unsigned)(size_t)(lds + bOff);

  bf16x8 fA[2][8], fB[2][4];

  // 12 asm ds_read_b128 into set P from ring-buffer base RB (compile-time const)
#define DSR(dst, base, off) \
  asm volatile("ds_read_b128 %0, %1 offset:" #off : "=&v"(dst) : "v"(base))
#define RDP(P, RB) do { \
    unsigned _ab = aAddr + (RB); \
    unsigned _bb = bAddr + (RB); \
    DSR(fA[P][0], _ab, 0);     DSR(fA[P][1], _ab, 2048); \
    DSR(fA[P][2], _ab, 4096);  DSR(fA[P][3], _ab, 6144); \
    DSR(fA[P][4], _ab, 8192);  DSR(fA[P][5], _ab, 10240); \
    DSR(fA[P][6], _ab, 12288); DSR(fA[P][7], _ab, 14336); \
    DSR(fB[P][0], _bb, 0);     DSR(fB[P][1], _bb, 2048); \
    DSR(fB[P][2], _bb, 4096);  DSR(fB[P][3], _bb, 6144); \
  } while (0)

#define MF(i, j, P) acc[i][j] = __builtin_amdgcn_mfma_f32_16x16x32_bf16(fA[P][i], fB[P][j], acc[i][j], 0, 0, 0)
#define MMP(P) do { \
    MF(0, 0, P); MF(0, 1, P); MF(0, 2, P); MF(0, 3, P); \
    MF(1, 0, P); MF(1, 1, P); MF(1, 2, P); MF(1, 3, P); \
    MF(2, 0, P); MF(2, 1, P); MF(2, 2, P); MF(2, 3, P); \
    MF(3, 0, P); MF(3, 1, P); MF(3, 2, P); MF(3, 3, P); \
    MF(4, 0, P); MF(4, 1, P); MF(4, 2, P); MF(4, 3, P); \
    MF(5, 0, P); MF(5, 1, P); MF(5, 2, P); MF(5, 3, P); \
    MF(6, 0, P); MF(6, 1, P); MF(6, 2, P); MF(6, 3, P); \
    MF(7, 0, P); MF(7, 1, P); MF(7, 2, P); MF(7, 3, P); \
  } while (0)

#define PHASE(RBB, SBB, PC, PN, KT) do { \
    RDP(PN, RBB); \
    STG(KT, SBB); \
    LGKM12(); \
    __builtin_amdgcn_sched_barrier(0); \
    __builtin_amdgcn_s_setprio(1); \
    MMP(PC); \
    __builtin_amdgcn_s_setprio(0); \
    VMCNT4(); \
    BAR(); \
  } while (0)

  f32x4 acc[8][4];
#pragma unroll
  for (int i = 0; i < 8; ++i)
#pragma unroll
    for (int j = 0; j < 4; ++j) acc[i][j] = (f32x4){0.f, 0.f, 0.f, 0.f};

  // ---- prologue: stage tiles 0,1,2; vmcnt(4) -> tiles 0,1 resident; read tile0 ----
  STG(0, 0); STG(1, 32768); STG(2, 65536);
  VMCNT4();
  BAR();
  RDP(0, 0);

#pragma unroll 1
  for (int u = 0; u < 32; ++u) {
    const int p = u << 2;
    PHASE(32768, 98304, 0, 1, (p + 3) & 127);   // rd tile p+1 (buf1), stg p+3 (buf3), MFMA tile p
    PHASE(65536, 0,     1, 0, (p + 4) & 127);   // rd p+2 (buf2), stg p+4 (buf0), MFMA p+1
    PHASE(98304, 32768, 0, 1, (p + 5) & 127);   // rd p+3 (buf3), stg p+5 (buf1), MFMA p+2
    PHASE(0,     65536, 1, 0, (p + 6) & 127);   // rd p+4 (buf0), stg p+6 (buf2), MFMA p+3
  }

  // ---- epilogue: C/D layout col = lane&15, row = (lane>>4)*4 + q ----
  const int crow = (lane >> 4) << 2;
  const int ccol = lane & 15;
#pragma unroll
  for (int i = 0; i < 8; ++i) {
#pragma unroll
    for (int j = 0; j < 4; ++j) {
      size_t base = (size_t)(m0 + wm * 128 + i * 16 + crow) * NDIM + (n0 + wn * 64 + j * 16 + ccol);
#pragma unroll
      for (int q = 0; q < 4; ++q) out[base + (size_t)q * NDIM] = acc[i][j][q];
    }
  }
}

extern "C" void kernel_launch(void* const* d_in, const int* in_sizes, int n_in,
                              void* d_out, int out_size, void* d_ws, size_t ws_size,
                              hipStream_t stream) {
  const float* x = (const float*)d_in[0];
  const float* g1 = (const float*)d_in[1];
  const float* g2 = (const float*)d_in[2];
  float* out = (float*)d_out;

  unsigned short* Wt = (unsigned short*)d_ws;
  unsigned short* Xb = (unsigned short*)d_ws + (size_t)KDIM * NDIM;

  prep_kernel<<<16384 + NDIM, 256, 0, stream>>>(x, g1, g2, Xb, Wt);
  gemm_kernel<<<(TOKENS / 256) * (NDIM / 256), 512, 0, stream>>>(Xb, Wt, out);
}